// Round 3
// baseline (3367.049 us; speedup 1.0000x reference)
//
#include <hip/hip_runtime.h>

#define NPTS   32768
#define DIM    256
#define KCODES 8192

#define BM 128
#define BN 512
#define BK 16

// ---------------- kernel 0: row squared-norms ----------------
// fl32( f64-sum of fl32(x_i^2) ): within ~1 ulp of numpy's fp32 pairwise sum.
// Per-row error is common-mode (a multiple of the final dist grid) -> argmin-safe.
__global__ __launch_bounds__(256) void norms_kernel(const float* __restrict__ src,
                                                    float* __restrict__ dst) {
  int row = blockIdx.x * 4 + (threadIdx.x >> 6);
  int lane = threadIdx.x & 63;
  float4 a = reinterpret_cast<const float4*>(src)[row * (DIM / 4) + lane];
  // fp32 squares first (numpy materializes fl(x*x) before summing)
  float sx = a.x * a.x, sy = a.y * a.y, sz = a.z * a.z, sw = a.w * a.w;
  double s = (double)sx + (double)sy + (double)sz + (double)sw;
#pragma unroll
  for (int m = 32; m; m >>= 1) s += __shfl_xor(s, m, 64);
  if (lane == 0) dst[row] = (float)s;
}

// ---------------- kernel 1: fused distance GEMM + argmin ----------------
// block: 512 threads = (ct 0..31 code-dir) x (pt 0..15 point-dir)
// per-thread micro-tile: 8 points x 16 codes
// point  p_local = pt*4 + (i>>2)*64  + (i&3)
// code   c_local = ct*4 + (j>>2)*128 + (j&3)
// Score replicates numpy fp32: s = fl32( fl32(h2+c2) - 2*dot ), dot = ascending-k
// sequential fma chain (bit-matches BLAS single-accumulator microkernel).
// Ties (same fp32 bits) resolve to LOWEST code index, like np.argmin.
__global__ __launch_bounds__(512, 2) void argmin_kernel(
    const float* __restrict__ h, const float* __restrict__ cb,
    const float* __restrict__ h2f, const float* __restrict__ c2f,
    int* __restrict__ out_idx, float* __restrict__ out_idx_f) {
  __shared__ float hs[BK][BM];   // 8 KB, k-major
  __shared__ float cs[BK][BN];   // 32 KB, k-major
  const int t = threadIdx.x;
  const int ct = t & 31;
  const int pt = t >> 5;
  const int p0 = blockIdx.x * BM;

  float best[8];
  int besti[8];
  float h2r[8];
#pragma unroll
  for (int i = 0; i < 8; ++i) {
    best[i] = 3.4e38f;
    besti[i] = 0;
    h2r[i] = h2f[p0 + pt * 4 + ((i >> 2) << 6) + (i & 3)];
  }

#pragma unroll 1
  for (int cc = 0; cc < KCODES / BN; ++cc) {
    const int c0 = cc * BN;
    float dot[8][16];
#pragma unroll
    for (int i = 0; i < 8; ++i)
#pragma unroll
      for (int j = 0; j < 16; ++j) dot[i][j] = 0.f;

#pragma unroll 1
    for (int dd = 0; dd < DIM / BK; ++dd) {
      const int d0 = dd * BK;
      // stage h tile (transposed scatter): 512 float4, one per thread
      {
        int p = t >> 2, k4 = (t & 3) << 2;
        float4 v = *reinterpret_cast<const float4*>(h + (p0 + p) * DIM + d0 + k4);
        hs[k4 + 0][p] = v.x; hs[k4 + 1][p] = v.y;
        hs[k4 + 2][p] = v.z; hs[k4 + 3][p] = v.w;
      }
      // stage c tile: 2048 float4, four per thread
#pragma unroll
      for (int l = 0; l < 4; ++l) {
        int F = t + l * 512;
        int c = F >> 2, k4 = (F & 3) << 2;
        float4 v = *reinterpret_cast<const float4*>(cb + (c0 + c) * DIM + d0 + k4);
        cs[k4 + 0][c] = v.x; cs[k4 + 1][c] = v.y;
        cs[k4 + 2][c] = v.z; cs[k4 + 3][c] = v.w;
      }
      __syncthreads();
#pragma unroll
      for (int k = 0; k < BK; ++k) {
        float hv[8], cv[16];
        *reinterpret_cast<float4*>(&hv[0]) = *reinterpret_cast<const float4*>(&hs[k][pt * 4]);
        *reinterpret_cast<float4*>(&hv[4]) = *reinterpret_cast<const float4*>(&hs[k][pt * 4 + 64]);
        *reinterpret_cast<float4*>(&cv[0])  = *reinterpret_cast<const float4*>(&cs[k][ct * 4]);
        *reinterpret_cast<float4*>(&cv[4])  = *reinterpret_cast<const float4*>(&cs[k][ct * 4 + 128]);
        *reinterpret_cast<float4*>(&cv[8])  = *reinterpret_cast<const float4*>(&cs[k][ct * 4 + 256]);
        *reinterpret_cast<float4*>(&cv[12]) = *reinterpret_cast<const float4*>(&cs[k][ct * 4 + 384]);
#pragma unroll
        for (int i = 0; i < 8; ++i)
#pragma unroll
          for (int j = 0; j < 16; ++j)
            dot[i][j] = fmaf(hv[i], cv[j], dot[i][j]);
      }
      __syncthreads();
    }
    // numpy-fp32 scores + running argmin (ascending code order -> first-min tiebreak)
#pragma unroll
    for (int j = 0; j < 16; ++j) {
      int cl = c0 + (ct << 2) + ((j >> 2) << 7) + (j & 3);
      float cc2 = c2f[cl];
#pragma unroll
      for (int i = 0; i < 8; ++i) {
        float A = h2r[i] + cc2;          // fl32(h2 + c2)
        float s = A - 2.0f * dot[i][j];  // fl32(A - 2*dot); fma-contraction bit-equal
        if (s < best[i]) { best[i] = s; besti[i] = cl; }
      }
    }
  }
  // cross-lane reduce over the 32 ct-lanes (same pt), lowest-index tiebreak
#pragma unroll
  for (int i = 0; i < 8; ++i) {
    float b1 = best[i];
    int i1 = besti[i];
#pragma unroll
    for (int m = 16; m; m >>= 1) {
      float so = __shfl_xor(b1, m, 64);
      int io = __shfl_xor(i1, m, 64);
      if (so < b1 || (so == b1 && io < i1)) { b1 = so; i1 = io; }
    }
    if (ct == 0) {
      int p = p0 + pt * 4 + ((i >> 2) << 6) + (i & 3);
      out_idx[p] = i1;
      out_idx_f[p] = (float)i1;
    }
  }
}

// ---------------- kernel 2: gather z, write z_q, masked sq-sum partials ----------------
__global__ __launch_bounds__(256) void gather_kernel(
    const float* __restrict__ h, const float* __restrict__ cb,
    const unsigned char* __restrict__ maskb, const int* __restrict__ idx,
    float* __restrict__ zq, float* __restrict__ partial) {
  int p = blockIdx.x * 4 + (threadIdx.x >> 6);
  int lane = threadIdx.x & 63;
  int ci = idx[p];
  float4 hv = reinterpret_cast<const float4*>(h)[p * (DIM / 4) + lane];
  float4 zv = reinterpret_cast<const float4*>(cb)[ci * (DIM / 4) + lane];
  float4 q;
  q.x = hv.x + (zv.x - hv.x);
  q.y = hv.y + (zv.y - hv.y);
  q.z = hv.z + (zv.z - hv.z);
  q.w = hv.w + (zv.w - hv.w);
  reinterpret_cast<float4*>(zq)[p * (DIM / 4) + lane] = q;
  float dx = hv.x - zv.x, dy = hv.y - zv.y, dz = hv.z - zv.z, dw = hv.w - zv.w;
  float s = (maskb[p] != 0) ? (dx * dx + dy * dy + dz * dz + dw * dw) : 0.f;
#pragma unroll
  for (int m = 32; m; m >>= 1) s += __shfl_xor(s, m, 64);
  __shared__ float bs[4];
  if (lane == 0) bs[threadIdx.x >> 6] = s;
  __syncthreads();
  if (threadIdx.x == 0) partial[blockIdx.x] = bs[0] + bs[1] + bs[2] + bs[3];
}

// ---------------- kernel 3: deterministic finalize ----------------
__global__ __launch_bounds__(256) void finalize_kernel(
    const float* __restrict__ partial, const unsigned char* __restrict__ maskb,
    float* __restrict__ out_losses) {
  __shared__ float red[256];
  __shared__ int redi[256];
  float s = 0.f;
  for (int i = threadIdx.x; i < NPTS / 4; i += 256) s += partial[i];
  int cnt = 0;
  for (int i = threadIdx.x; i < NPTS; i += 256) cnt += (maskb[i] != 0);
  red[threadIdx.x] = s;
  redi[threadIdx.x] = cnt;
  __syncthreads();
  for (int step = 128; step; step >>= 1) {
    if (threadIdx.x < step) {
      red[threadIdx.x] += red[threadIdx.x + step];
      redi[threadIdx.x] += redi[threadIdx.x + step];
    }
    __syncthreads();
  }
  if (threadIdx.x == 0) {
    float denom = (float)redi[0] * (float)DIM + 1e-8f;
    float loss = red[0] / denom;
    out_losses[0] = loss;   // commit_loss
    out_losses[1] = loss;   // codebook_loss (identical in forward)
  }
}

extern "C" void kernel_launch(void* const* d_in, const int* in_sizes, int n_in,
                              void* d_out, int out_size, void* d_ws, size_t ws_size,
                              hipStream_t stream) {
  const float* h = (const float*)d_in[0];
  const unsigned char* maskb = (const unsigned char*)d_in[1];
  const float* cb = (const float*)d_in[2];

  float* out = (float*)d_out;
  float* zq = out;                              // NPTS*DIM
  float* out_idx_f = out + NPTS * DIM;          // NPTS
  float* out_losses = out + NPTS * DIM + NPTS;  // 2

  char* ws = (char*)d_ws;
  float* h2f = (float*)(ws + 0);               // 32768 f [0,128KB)
  float* c2f = (float*)(ws + (128 << 10));     // 8192 f  [128KB,160KB)
  int* idx = (int*)(ws + (160 << 10));         // 32768 i [160KB,288KB)
  float* partial = (float*)(ws + (288 << 10)); // 8192 f  [288KB,320KB)

  hipLaunchKernelGGL(norms_kernel, dim3(NPTS / 4), dim3(256), 0, stream, h, h2f);
  hipLaunchKernelGGL(norms_kernel, dim3(KCODES / 4), dim3(256), 0, stream, cb, c2f);
  hipLaunchKernelGGL(argmin_kernel, dim3(NPTS / BM), dim3(512), 0, stream,
                     h, cb, h2f, c2f, idx, out_idx_f);
  hipLaunchKernelGGL(gather_kernel, dim3(NPTS / 4), dim3(256), 0, stream,
                     h, cb, maskb, idx, zq, partial);
  hipLaunchKernelGGL(finalize_kernel, dim3(1), dim3(256), 0, stream,
                     partial, maskb, out_losses);
}